// Round 13
// baseline (5596.362 us; speedup 1.0000x reference)
//
#include <hip/hip_runtime.h>

namespace {

constexpr int kB = 4, kS = 2048, kD = 1024, kH = 16, kF = 4096, kM = 1024;
constexpr int kBS = kB * kS;   // 8192 rows
constexpr int kBM = kB * kM;   // 4096 rows

#define DEV __device__ __forceinline__

DEV float bf2f(unsigned short u){ unsigned int i = ((unsigned int)u) << 16; float f; __builtin_memcpy(&f, &i, 4); return f; }
DEV unsigned short f2bf(float f){ unsigned int i; __builtin_memcpy(&i, &f, 4); return (unsigned short)((i + 0x7fffu + ((i >> 16) & 1u)) >> 16); }
DEV float gelu_f(float x){ float u = 0.7978845608028654f * (x + 0.044715f * x * x * x); return 0.5f * x * (1.0f + tanhf(u)); }
DEV float sigmoid_f(float x){ return 1.0f / (1.0f + __expf(-x)); }

typedef __attribute__((ext_vector_type(8))) short bf16x8;
typedef __attribute__((ext_vector_type(4))) float f32x4;
typedef __attribute__((address_space(1))) const unsigned char gas_u8;
typedef __attribute__((address_space(3))) unsigned char las_u8;

// ---------------- weight transpose (fp32 [K,N] -> bf16 [N,K]) ----------------
__global__ __launch_bounds__(256) void k_transpose_bf16(const float* __restrict__ W, unsigned short* __restrict__ Wt, int K, int N){
  __shared__ float tile[32][33];
  int n0 = blockIdx.x * 32, k0 = blockIdx.y * 32;
  int tx = threadIdx.x, ty = threadIdx.y;
  for (int i = ty; i < 32; i += 8) tile[i][tx] = W[(size_t)(k0 + i) * N + n0 + tx];
  __syncthreads();
  for (int i = ty; i < 32; i += 8) Wt[(size_t)(n0 + i) * K + k0 + tx] = f2bf(tile[tx][i]);
}

// ---------------- rmsnorm (fp32 in -> bf16 out), one row per block ----------------
__global__ __launch_bounds__(256) void k_rmsnorm(const float* __restrict__ x, const float* __restrict__ scale, unsigned short* __restrict__ out){
  int row = blockIdx.x;
  int t = threadIdx.x;
  float4 v = ((const float4*)(x + (size_t)row * kD))[t];
  float ss = v.x*v.x + v.y*v.y + v.z*v.z + v.w*v.w;
  for (int o = 32; o > 0; o >>= 1) ss += __shfl_xor(ss, o);
  __shared__ float red[4];
  int wave = t >> 6, lane = t & 63;
  if (lane == 0) red[wave] = ss;
  __syncthreads();
  float tot = red[0] + red[1] + red[2] + red[3];
  float r = rsqrtf(tot * (1.0f / kD) + 1e-6f);
  float4 s = ((const float4*)scale)[t];
  ushort4 o4;
  o4.x = f2bf(v.x * r * s.x); o4.y = f2bf(v.y * r * s.y);
  o4.z = f2bf(v.z * r * s.z); o4.w = f2bf(v.w * r * s.w);
  *(ushort4*)(out + (size_t)row * kD + t * 4) = o4;
}

// ---------------- fp32 -> bf16 convert ----------------
__global__ __launch_bounds__(256) void k_f32_to_bf16(const float* __restrict__ in, unsigned short* __restrict__ out, int n4){
  int i = blockIdx.x * 256 + threadIdx.x;
  int stride = gridDim.x * 256;
  for (; i < n4; i += stride){
    float4 v = ((const float4*)in)[i];
    ushort4 o; o.x = f2bf(v.x); o.y = f2bf(v.y); o.z = f2bf(v.z); o.w = f2bf(v.w);
    ((ushort4*)out)[i] = o;
  }
}

// ---------------- combine: xres = xres(mem_out) + x + h + 0.1*v ----------------
__global__ __launch_bounds__(256) void k_combine(float* __restrict__ xres, const float* __restrict__ x,
                                                 const float* __restrict__ h, const unsigned short* __restrict__ v, int n4){
  int i = blockIdx.x * 256 + threadIdx.x;
  int stride = gridDim.x * 256;
  for (; i < n4; i += stride){
    float4 a = ((float4*)xres)[i];
    float4 xv = ((const float4*)x)[i];
    float4 hv = ((const float4*)h)[i];
    ushort4 vv = ((const ushort4*)v)[i];
    a.x += xv.x + hv.x + 0.1f * bf2f(vv.x);
    a.y += xv.y + hv.y + 0.1f * bf2f(vv.y);
    a.z += xv.z + hv.z + 0.1f * bf2f(vv.z);
    a.w += xv.w + hv.w + 0.1f * bf2f(vv.w);
    ((float4*)xres)[i] = a;
  }
}

// ---------------- generic bf16 MFMA GEMM: C[M,N] = epi(A[M,K] @ Bt[N,K]^T + bias) ----------------
// EPI: 0 f32 | 1 bf16 | 2 gelu->bf16 | 3 sigmoid->f32 | 4 out1=clip(out1*sigmoid(v)) |
//      5 f32+bf16 dual | 6 out1=src+v | 7 out1+=v | 8 fused qkvz (N=4096, route by n-block) |
//      9 bf16 transposed V-head write: out2 = vhT[b][h][d][key]
template<int EPI>
__global__ __launch_bounds__(256) void gemm_kernel(
    const unsigned short* __restrict__ A, int lda,
    const unsigned short* __restrict__ Bt, int ldb,
    const float* __restrict__ bias,
    float* __restrict__ out1, unsigned short* __restrict__ out2,
    const float* __restrict__ src,
    int Mdim, int Ndim, int Kdim,
    const float* __restrict__ b_k = nullptr,
    const float* __restrict__ b_v = nullptr,
    const float* __restrict__ b_z = nullptr,
    unsigned short* __restrict__ o_k = nullptr,
    unsigned short* __restrict__ o_v = nullptr,
    unsigned short* __restrict__ o_zb = nullptr)
{
  __shared__ unsigned short As[128 * 32];
  __shared__ unsigned short Bs[128 * 32];
  const int t = threadIdx.x;
  const int wave = t >> 6, lane = t & 63;
  const int m0 = blockIdx.y * 128, n0 = blockIdx.x * 128;
  const int wr = (wave >> 1) * 64, wc = (wave & 1) * 64;
  const int lr = lane & 15, lk = lane >> 4;

  f32x4 acc[4][4];
  #pragma unroll
  for (int m = 0; m < 4; ++m)
    #pragma unroll
    for (int n = 0; n < 4; ++n) acc[m][n] = (f32x4){0.f, 0.f, 0.f, 0.f};

  const int r0 = t >> 2, s0 = (t & 3) * 8;
  const int r1 = 64 + r0;
  las_u8* lA0 = (las_u8*)(void*)(As + r0 * 32 + s0);
  las_u8* lA1 = (las_u8*)(void*)(As + r1 * 32 + s0);
  las_u8* lB0 = (las_u8*)(void*)(Bs + r0 * 32 + s0);
  las_u8* lB1 = (las_u8*)(void*)(Bs + r1 * 32 + s0);

  for (int k0 = 0; k0 < Kdim; k0 += 32){
    __syncthreads();
    __builtin_amdgcn_global_load_lds((gas_u8*)(const void*)(A  + (size_t)(m0 + r0) * lda + k0 + s0), lA0, 16, 0, 0);
    __builtin_amdgcn_global_load_lds((gas_u8*)(const void*)(A  + (size_t)(m0 + r1) * lda + k0 + s0), lA1, 16, 0, 0);
    __builtin_amdgcn_global_load_lds((gas_u8*)(const void*)(Bt + (size_t)(n0 + r0) * ldb + k0 + s0), lB0, 16, 0, 0);
    __builtin_amdgcn_global_load_lds((gas_u8*)(const void*)(Bt + (size_t)(n0 + r1) * ldb + k0 + s0), lB1, 16, 0, 0);
    __syncthreads();
    bf16x8 af[4], bfr[4];
    #pragma unroll
    for (int m = 0; m < 4; ++m) af[m] = *(const bf16x8*)(As + (wr + m * 16 + lr) * 32 + lk * 8);
    #pragma unroll
    for (int n = 0; n < 4; ++n) bfr[n] = *(const bf16x8*)(Bs + (wc + n * 16 + lr) * 32 + lk * 8);
    #pragma unroll
    for (int m = 0; m < 4; ++m)
      #pragma unroll
      for (int n = 0; n < 4; ++n)
        acc[m][n] = __builtin_amdgcn_mfma_f32_16x16x32_bf16(af[m], bfr[n], acc[m][n], 0, 0, 0);
  }

  const float* bsel = bias;
  unsigned short* osel = out2;
  int sel = 0;
  if constexpr (EPI == 8){
    sel = n0 >> 10;
    bsel = (sel == 0) ? bias : (sel == 1) ? b_k : (sel == 2) ? b_v : b_z;
    osel = (sel == 0) ? out2 : (sel == 1) ? o_k : (sel == 2) ? o_v : o_zb;
  }

  #pragma unroll
  for (int m = 0; m < 4; ++m){
    #pragma unroll
    for (int n = 0; n < 4; ++n){
      int col = n0 + wc + n * 16 + lr;
      float bv;
      if constexpr (EPI == 8) bv = bsel[col & 1023];
      else bv = bias ? bias[col] : 0.f;
      #pragma unroll
      for (int r = 0; r < 4; ++r){
        int rowg = m0 + wr + m * 16 + lk * 4 + r;
        size_t off = (size_t)rowg * Ndim + col;
        float v = acc[m][n][r] + bv;
        if constexpr (EPI == 0) out1[off] = v;
        else if constexpr (EPI == 1) out2[off] = f2bf(v);
        else if constexpr (EPI == 2) out2[off] = f2bf(gelu_f(v));
        else if constexpr (EPI == 3) out1[off] = sigmoid_f(v);
        else if constexpr (EPI == 4){ float g = out1[off] * sigmoid_f(v); out1[off] = fminf(fmaxf(g, 1e-6f), 1.0f - 1e-6f); }
        else if constexpr (EPI == 5){ out1[off] = v; out2[off] = f2bf(v); }
        else if constexpr (EPI == 6) out1[off] = src[off] + v;
        else if constexpr (EPI == 7) out1[off] += v;
        else if constexpr (EPI == 8){
          size_t off8 = (size_t)rowg * 1024 + (col & 1023);
          if (sel == 3){ out1[off8] = v; osel[off8] = f2bf(v); }
          else osel[off8] = f2bf(v);
        }
        else if constexpr (EPI == 9){
          int bb = rowg >> 10, key = rowg & 1023, hh = col >> 6, dd = col & 63;
          out2[(((size_t)bb * 16 + hh) * 64 + dd) * 1024 + key] = f2bf(v);
        }
      }
    }
  }
}

// ---------------- sequential gated scan v9: pipelined poll rounds ----------------
// R11 skeleton (parallel retry, post-poll inputs, 2 barriers, wave0 finalize) with the
// poll split into 4 row-major rounds interleaved with the 4 matching MAC slices:
//  - lane polls rows {ibase + 64r + lane} (r=0..3); all 4 row-loads issued upfront.
//  - round r: __any-retry row r only -> land to hl (same-wave DS, in-order) -> MAC
//    slice r (j in [8r,8r+8) reads exactly h-rows [64r,64r+64)).
//  - later rounds' loads stay in flight under earlier MAC slices; clean-path checks
//    only wait on loads <= their own (vmcnt in-order; inputs/retries are newer).
//  - inputs (gz/z/gamma) issued after round 0 -> ~600cy of MAC+reduce hide them
//    before the red-barrier's vmcnt drain.
__global__ __launch_bounds__(256) void k_scan(const float* __restrict__ wgh,
                                              const float* __restrict__ gz,
                                              float* __restrict__ zh /* z in, h out (in-place) */,
                                              const float* __restrict__ gamma,
                                              const float* __restrict__ bgh,
                                              unsigned long long* __restrict__ hpub){
  __shared__ unsigned short wsl[1024 * 32]; // [i][col] bf16, 64KB
  __shared__ float hl[1024];
  __shared__ float red[4][32];
  const int t = threadIdx.x;
  const int bid = blockIdx.x;
  const int b = bid & 3, slc = bid >> 2;   // batch-major interleave
  const int colg0 = slc * 32;

  for (int idx = t; idx < 32768; idx += 256){
    int k = idx >> 5, c = idx & 31;
    wsl[idx] = f2bf(wgh[(size_t)k * 1024 + colg0 + c]);
  }
  const float bghv = (t < 32) ? bgh[colg0 + t] : 0.f;
  const int lane = t & 63, w = t >> 6;
  const int lgrp = lane >> 3;   // 0..7 row offset within 8-row group (h broadcast)
  const int lcol = lane & 7;    // 0..7 -> bf16 cols 4*lcol..+3
  const int ibase = w * 256;
  __syncthreads();

  for (int tt = 0; tt < kS; ++tt){
    float a0 = 0.f, a1 = 0.f, a2 = 0.f, a3 = 0.f;
    float gzv = 0.f, zv = 0.f, gv = 0.f;
    size_t inidx = 0;
    const unsigned short* wb = wsl + ibase * 32;

    // MAC slice r: j in [8r, 8r+8)
#define MACSLICE(R) { \
      _Pragma("unroll") \
      for (int j = 8*(R); j < 8*(R) + 8; ++j){ \
        int i = j * 8 + lgrp; \
        float hv = hl[ibase + i]; \
        uint2 ww = *(const uint2*)(wb + i * 32 + lcol * 4); \
        a0 += hv * bf2f((unsigned short)(ww.x & 0xffffu)); \
        a1 += hv * bf2f((unsigned short)(ww.x >> 16)); \
        a2 += hv * bf2f((unsigned short)(ww.y & 0xffffu)); \
        a3 += hv * bf2f((unsigned short)(ww.y >> 16)); \
      } }

    if (tt > 0){
      const unsigned want = (unsigned)(tt - 1);
      unsigned long long* pb = hpub + (((size_t)((tt - 1) & 1)) * kB + b) * 1024 + ibase + lane;
      // issue all 4 round loads upfront (in flight together)
      unsigned long long pv0 = __hip_atomic_load(pb +   0, __ATOMIC_RELAXED, __HIP_MEMORY_SCOPE_AGENT);
      unsigned long long pv1 = __hip_atomic_load(pb +  64, __ATOMIC_RELAXED, __HIP_MEMORY_SCOPE_AGENT);
      unsigned long long pv2 = __hip_atomic_load(pb + 128, __ATOMIC_RELAXED, __HIP_MEMORY_SCOPE_AGENT);
      unsigned long long pv3 = __hip_atomic_load(pb + 192, __ATOMIC_RELAXED, __HIP_MEMORY_SCOPE_AGENT);
      // round 0
      while (__any((unsigned)(pv0 >> 32) != want))
        pv0 = __hip_atomic_load(pb + 0, __ATOMIC_RELAXED, __HIP_MEMORY_SCOPE_AGENT);
      hl[ibase + lane] = __uint_as_float((unsigned)pv0);
      asm volatile("" ::: "memory");
      // inputs issued here: newer than pv1-3 (never gate their clean checks);
      // ~600cy of MAC+reduce ahead to hide their HBM latency before the barrier drain
      if (t < 32){
        inidx = ((size_t)b * kS + tt) * 1024 + colg0 + t;
        gzv = gz[inidx]; zv = zh[inidx]; gv = gamma[inidx];
      }
      asm volatile("" ::: "memory");
      MACSLICE(0)
      // round 1
      while (__any((unsigned)(pv1 >> 32) != want))
        pv1 = __hip_atomic_load(pb + 64, __ATOMIC_RELAXED, __HIP_MEMORY_SCOPE_AGENT);
      hl[ibase + 64 + lane] = __uint_as_float((unsigned)pv1);
      MACSLICE(1)
      // round 2
      while (__any((unsigned)(pv2 >> 32) != want))
        pv2 = __hip_atomic_load(pb + 128, __ATOMIC_RELAXED, __HIP_MEMORY_SCOPE_AGENT);
      hl[ibase + 128 + lane] = __uint_as_float((unsigned)pv2);
      MACSLICE(2)
      // round 3
      while (__any((unsigned)(pv3 >> 32) != want))
        pv3 = __hip_atomic_load(pb + 192, __ATOMIC_RELAXED, __HIP_MEMORY_SCOPE_AGENT);
      hl[ibase + 192 + lane] = __uint_as_float((unsigned)pv3);
      MACSLICE(3)
    } else {
      hl[ibase + lane] = 0.f; hl[ibase + 64 + lane] = 0.f;
      hl[ibase + 128 + lane] = 0.f; hl[ibase + 192 + lane] = 0.f;
      if (t < 32){
        inidx = ((size_t)b * kS) * 1024 + colg0 + t;
        gzv = gz[inidx]; zv = zh[inidx]; gv = gamma[inidx];
      }
      MACSLICE(0) MACSLICE(1) MACSLICE(2) MACSLICE(3)
    }
#undef MACSLICE

    // reduce across lanes sharing the same cols (stride-8 lanes)
    for (int o = 8; o < 64; o <<= 1){
      a0 += __shfl_xor(a0, o); a1 += __shfl_xor(a1, o);
      a2 += __shfl_xor(a2, o); a3 += __shfl_xor(a3, o);
    }
    if (lane < 8){
      red[w][lane * 4 + 0] = a0; red[w][lane * 4 + 1] = a1;
      red[w][lane * 4 + 2] = a2; red[w][lane * 4 + 3] = a3;
    }
    __syncthreads();

    if (t < 32){
      float sum = red[0][t] + red[1][t] + red[2][t] + red[3][t];
      float gate = sigmoid_f(gzv + sum + bghv);
      float hp = hl[colg0 + t];
      float ht = (1.0f - gate) * hp + gate * zv + gv * hp;
      ht = fminf(fmaxf(ht, -100.0f), 100.0f);
      zh[inidx] = ht;
      unsigned long long pv = ((unsigned long long)(unsigned)tt << 32)
                            | (unsigned long long)__float_as_uint(ht);
      __hip_atomic_store(hpub + (((size_t)(tt & 1)) * kB + b) * 1024 + colg0 + t, pv,
                         __ATOMIC_RELAXED, __HIP_MEMORY_SCOPE_AGENT);
    }
    __syncthreads();  // protects red/hl WAR for next iteration
  }
}

// ---------------- MFMA flash attention: block = (64 q-rows, h, b); 4 waves x 16 rows ----------------
__global__ __launch_bounds__(256) void k_attn_mfma(const unsigned short* __restrict__ q,
                                                   const unsigned short* __restrict__ kh,
                                                   const unsigned short* __restrict__ vhT,
                                                   unsigned short* __restrict__ ao){
  __shared__ unsigned short Qs[2][64][32];
  __shared__ unsigned short Ks[2][128][32];
  __shared__ unsigned short Vt[4][64][32];
  __shared__ unsigned short Ps[4][4][16][32];
  const int t = threadIdx.x;
  const int qt = blockIdx.x, h = blockIdx.y, b = blockIdx.z;
  const int lane = t & 63, w = t >> 6;
  const int lk = lane >> 4, lr = lane & 15;

  for (int i = t; i < 512; i += 256){
    int row = i >> 3, cg = (i & 7) * 8;
    *(uint4*)&Qs[cg >> 5][row][cg & 31] =
      *(const uint4*)(q + ((size_t)(b * kS + qt * 64 + row)) * kD + h * 64 + cg);
  }

  f32x4 acc_o[4];
  #pragma unroll
  for (int n = 0; n < 4; ++n) acc_o[n] = (f32x4){0.f, 0.f, 0.f, 0.f};
  float m_[4], l_[4];
  #pragma unroll
  for (int r = 0; r < 4; ++r){ m_[r] = -3e38f; l_[r] = 0.f; }

  for (int c = 0; c < 8; ++c){
    __syncthreads();
    for (int i = t; i < 1024; i += 256){
      int key = i >> 3, cg = (i & 7) * 8;
      *(uint4*)&Ks[cg >> 5][key][cg & 31] =
        *(const uint4*)(kh + ((size_t)(b * kM + c * 128 + key)) * kD + h * 64 + cg);
    }
    for (int i = t; i < 1024; i += 256){
      int d = i >> 4, kg = (i & 15) * 8;
      *(uint4*)&Vt[kg >> 5][d][kg & 31] =
        *(const uint4*)(vhT + (((size_t)(b * 16 + h)) * 64 + d) * 1024 + c * 128 + kg);
    }
    __syncthreads();

    f32x4 accs[8];
    #pragma unroll
    for (int n = 0; n < 8; ++n) accs[n] = (f32x4){0.f, 0.f, 0.f, 0.f};
    #pragma unroll
    for (int kk = 0; kk < 2; ++kk){
      bf16x8 aq = *(const bf16x8*)&Qs[kk][16 * w + lr][lk * 8];
      #pragma unroll
      for (int n = 0; n < 8; ++n){
        bf16x8 bk8 = *(const bf16x8*)&Ks[kk][16 * n + lr][lk * 8];
        accs[n] = __builtin_amdgcn_mfma_f32_16x16x32_bf16(aq, bk8, accs[n], 0, 0, 0);
      }
    }

    #pragma unroll
    for (int n = 0; n < 8; ++n)
      #pragma unroll
      for (int r = 0; r < 4; ++r) accs[n][r] *= 0.125f;
    float mnew[4], alpha[4], psum[4];
    #pragma unroll
    for (int r = 0; r < 4; ++r){
      float mx = accs[0][r];
      #pragma unroll
      for (int n = 1; n < 8; ++n) mx = fmaxf(mx, accs[n][r]);
      #pragma unroll
      for (int o = 1; o < 16; o <<= 1) mx = fmaxf(mx, __shfl_xor(mx, o));
      mnew[r] = fmaxf(m_[r], mx);
      alpha[r] = __expf(m_[r] - mnew[r]);
      m_[r] = mnew[r];
      psum[r] = 0.f;
    }
    #pragma unroll
    for (int n = 0; n < 8; ++n){
      #pragma unroll
      for (int r = 0; r < 4; ++r){
        float p = __expf(accs[n][r] - mnew[r]);
        psum[r] += p;
        Ps[w][n >> 1][lk * 4 + r][16 * (n & 1) + lr] = f2bf(p);
      }
    }
    #pragma unroll
    for (int r = 0; r < 4; ++r){
      float s = psum[r];
      #pragma unroll
      for (int o = 1; o < 16; o <<= 1) s += __shfl_xor(s, o);
      l_[r] = l_[r] * alpha[r] + s;
      #pragma unroll
      for (int n = 0; n < 4; ++n) acc_o[n][r] *= alpha[r];
    }

    #pragma unroll
    for (int kk = 0; kk < 4; ++kk){
      bf16x8 ap = *(const bf16x8*)&Ps[w][kk][lr][lk * 8];
      #pragma unroll
      for (int n = 0; n < 4; ++n){
        bf16x8 bv8 = *(const bf16x8*)&Vt[kk][16 * n + lr][lk * 8];
        acc_o[n] = __builtin_amdgcn_mfma_f32_16x16x32_bf16(ap, bv8, acc_o[n], 0, 0, 0);
      }
    }
  }

  #pragma unroll
  for (int n = 0; n < 4; ++n){
    #pragma unroll
    for (int r = 0; r < 4; ++r){
      size_t off = ((size_t)(b * kS + qt * 64 + 16 * w + lk * 4 + r)) * kD + h * 64 + 16 * n + lr;
      ao[off] = f2bf(acc_o[n][r] / l_[r]);
    }
  }
}

} // namespace

extern "C" void kernel_launch(void* const* d_in, const int* in_sizes, int n_in,
                              void* d_out, int out_size, void* d_ws, size_t ws_size,
                              hipStream_t stream){
  (void)in_sizes; (void)n_in; (void)out_size;
  const float* x    = (const float*)d_in[0];
  const float* memk = (const float*)d_in[1];
  const float* memv = (const float*)d_in[2];
  const float* n1   = (const float*)d_in[3];
  const float* n2   = (const float*)d_in[4];
  const float* wq   = (const float*)d_in[5];   const float* bq  = (const float*)d_in[6];
  const float* wk   = (const float*)d_in[7];   const float* bk  = (const float*)d_in[8];
  const float* wv   = (const float*)d_in[9];   const float* bv  = (const float*)d_in[10];
  const float* wz   = (const float*)d_in[11];  const float* bz  = (const float*)d_in[12];
  const float* wgz  = (const float*)d_in[13];  const float* bgz = (const float*)d_in[14];
  const float* wgh  = (const float*)d_in[15];  const float* bgh = (const float*)d_in[16];
  const float* wg1  = (const float*)d_in[17];  const float* bg1 = (const float*)d_in[18];
  const float* wg2  = (const float*)d_in[19];  const float* bg2 = (const float*)d_in[20];
  const float* wc1  = (const float*)d_in[21];  const float* bc1 = (const float*)d_in[22];
  const float* wc2  = (const float*)d_in[23];  const float* bc2 = (const float*)d_in[24];
  const float* wak  = (const float*)d_in[25];  const float* bak = (const float*)d_in[26];
  const float* wav  = (const float*)d_in[27];  const float* bav = (const float*)d_in[28];
  const float* wao  = (const float*)d_in[29];  const float* bao = (const float*)d_in[30];
  const float* w1   = (const float*)d_in[31];  const float* b1  = (const float*)d_in[32];
  const float* w2   = (const float*)d_in[33];  const float* b2  = (const float*)d_in[34];
  float* outp = (float*)d_out;
  char* ws = (char*)d_ws;
  const size_t MBy = 1024ull * 1024ull;
  if (ws_size < 252 * MBy) return; // need 252MB scratch

  // ---- workspace layout (time-multiplexed regions) ----
  unsigned short* wq_t  = (unsigned short*)(ws + 0 * MBy);   // wq/wk/wv/wz contiguous: fused N=4096 Bt
  unsigned short* wk_t  = (unsigned short*)(ws + 2 * MBy);
  unsigned short* wv_t  = (unsigned short*)(ws + 4 * MBy);
  unsigned short* wz_t  = (unsigned short*)(ws + 6 * MBy);
  unsigned short* wgz_t = (unsigned short*)(ws + 8 * MBy);
  unsigned short* wak_t = (unsigned short*)(ws + 10 * MBy);
  unsigned short* wav_t = (unsigned short*)(ws + 12 * MBy);
  unsigned short* wao_t = (unsigned short*)(ws + 14 * MBy);
  unsigned short* wg1_t = (unsigned short*)(ws + 16 * MBy);
  unsigned short* wg2_t = (unsigned short*)(ws + 16 * MBy + 524288);
  unsigned short* wc1_t = (unsigned short*)(ws + 16 * MBy + 2 * 524288);
  unsigned short* wc2_t = (unsigned short*)(ws + 16 * MBy + 3 * 524288);
  unsigned short* w1_t  = (unsigned short*)(ws + 18 * MBy);
  unsigned short* w2_t  = (unsigned short*)(ws + 26 * MBy);
  unsigned long long* hpub = (unsigned long long*)(ws + 34 * MBy); // 64KB
  unsigned short* xn    = (unsigned short*)(ws + 40 * MBy);
  unsigned short* memk_b= (unsigned short*)(ws + 40 * MBy);
  unsigned short* memv_b= (unsigned short*)(ws + 48 * MBy);
  unsigned short* ao    = (unsigned short*)(ws + 40 * MBy);   // after kh/vhT GEMMs consume memk_b/memv_b
  unsigned short* qb_   = (unsigned short*)(ws + 56 * MBy);
  unsigned short* xn2   = (unsigned short*)(ws + 56 * MBy);
  unsigned short* kb_   = (unsigned short*)(ws + 72 * MBy);
  unsigned short* khb   = (unsigned short*)(ws + 72 * MBy);
  unsigned short* vhT   = (unsigned short*)(ws + 80 * MBy);   // [b][h][d][key] 8MB
  unsigned short* vb_   = (unsigned short*)(ws + 88 * MBy);
  float*          zf    = (float*)(ws + 104 * MBy);
  unsigned short* zb_   = (unsigned short*)(ws + 136 * MBy);
  unsigned short* mid   = (unsigned short*)(ws + 136 * MBy);
  float*          gzf   = (float*)(ws + 152 * MBy);
  float*          gmf   = (float*)(ws + 184 * MBy);
  unsigned short* g1b   = (unsigned short*)(ws + 216 * MBy);
  float*          xres  = (float*)(ws + 220 * MBy);

  dim3 tb(32, 8);
  // ---- weight transposes (wgh consumed directly by k_scan) ----
  k_transpose_bf16<<<dim3(32, 32), tb, 0, stream>>>(wq,  wq_t,  1024, 1024);
  k_transpose_bf16<<<dim3(32, 32), tb, 0, stream>>>(wk,  wk_t,  1024, 1024);
  k_transpose_bf16<<<dim3(32, 32), tb, 0, stream>>>(wv,  wv_t,  1024, 1024);
  k_transpose_bf16<<<dim3(32, 32), tb, 0, stream>>>(wz,  wz_t,  1024, 1024);
  k_transpose_bf16<<<dim3(32, 32), tb, 0, stream>>>(wgz, wgz_t, 1024, 1024);
  k_transpose_bf16<<<dim3(32, 32), tb, 0, stream>>>(wak, wak_t, 1024, 1024);
  k_transpose_bf16<<<dim3(32, 32), tb, 0, stream>>>(wav, wav_t, 1024, 1024);
  k_transpose_bf16<<<dim3(32, 32), tb, 0, stream>>>(wao, wao_t, 1024, 1024);
  k_transpose_bf16<<<dim3(8, 32),  tb, 0, stream>>>(wg1, wg1_t, 1024, 256);
  k_transpose_bf16<<<dim3(32, 8),  tb, 0, stream>>>(wg2, wg2_t, 256, 1024);
  k_transpose_bf16<<<dim3(8, 32),  tb, 0, stream>>>(wc1, wc1_t, 1024, 256);
  k_transpose_bf16<<<dim3(32, 8),  tb, 0, stream>>>(wc2, wc2_t, 256, 1024);
  k_transpose_bf16<<<dim3(128, 32),tb, 0, stream>>>(w1,  w1_t,  1024, 4096);
  k_transpose_bf16<<<dim3(32, 128),tb, 0, stream>>>(w2,  w2_t,  4096, 1024);

  // ---- norm + fused q/k/v/z projection ----
  k_rmsnorm<<<kBS, 256, 0, stream>>>(x, n1, xn);
  gemm_kernel<8><<<dim3(32, 64), 256, 0, stream>>>(xn, 1024, wq_t, 1024, bq, zf, qb_, nullptr,
                                                   kBS, 4096, 1024, bk, bv, bz, kb_, vb_, zb_);

  // ---- gate_z_seq and gamma ----
  gemm_kernel<0><<<dim3(8, 64), 256, 0, stream>>>(zb_, 1024, wgz_t, 1024, bgz, gzf, nullptr, nullptr, kBS, 1024, 1024);
  gemm_kernel<2><<<dim3(2, 64), 256, 0, stream>>>(zb_, 1024, wg1_t, 1024, bg1, nullptr, g1b, nullptr, kBS, 256, 1024);
  gemm_kernel<3><<<dim3(8, 64), 256, 0, stream>>>(g1b, 256, wg2_t, 256, bg2, gmf, nullptr, nullptr, kBS, 1024, 256);
  gemm_kernel<2><<<dim3(2, 64), 256, 0, stream>>>(kb_, 1024, wc1_t, 1024, bc1, nullptr, g1b, nullptr, kBS, 256, 1024);
  gemm_kernel<4><<<dim3(8, 64), 256, 0, stream>>>(g1b, 256, wc2_t, 256, bc2, gmf, nullptr, nullptr, kBS, 1024, 256);

  // ---- sequential scan (h written in-place over z; hpub re-tagged each launch) ----
  hipMemsetAsync(hpub, 0xFF, 65536, stream);
  k_scan<<<128, 256, 0, stream>>>(wgh, gzf, zf, gmf, bgh, hpub);

  // ---- memory attention (MFMA flash; V written transposed by EPI 9) ----
  k_f32_to_bf16<<<1024, 256, 0, stream>>>(memk, memk_b, kBM * kD / 4);
  k_f32_to_bf16<<<1024, 256, 0, stream>>>(memv, memv_b, kBM * kD / 4);
  gemm_kernel<1><<<dim3(8, 32), 256, 0, stream>>>(memk_b, 1024, wak_t, 1024, bak, nullptr, khb, nullptr, kBM, 1024, 1024);
  gemm_kernel<9><<<dim3(8, 32), 256, 0, stream>>>(memv_b, 1024, wav_t, 1024, bav, nullptr, vhT, nullptr, kBM, 1024, 1024);
  k_attn_mfma<<<dim3(32, 16, 4), 256, 0, stream>>>(qb_, khb, vhT, ao);
  gemm_kernel<0><<<dim3(8, 64), 256, 0, stream>>>(ao, 1024, wao_t, 1024, bao, xres, nullptr, nullptr, kBS, 1024, 1024);

  // ---- combine + norm2 + FFN (F split in two 2048 chunks to bound scratch) ----
  k_combine<<<2048, 256, 0, stream>>>(xres, x, zf, vb_, kBS * kD / 4);
  k_rmsnorm<<<kBS, 256, 0, stream>>>(xres, n2, xn2);
  gemm_kernel<2><<<dim3(16, 64), 256, 0, stream>>>(xn2, 1024, w1_t, 1024, b1, nullptr, mid, nullptr, kBS, 2048, 1024);
  gemm_kernel<6><<<dim3(8, 64), 256, 0, stream>>>(mid, 2048, w2_t, 4096, b2, outp, nullptr, xres, kBS, 1024, 2048);
  gemm_kernel<2><<<dim3(16, 64), 256, 0, stream>>>(xn2, 1024, w1_t + (size_t)2048 * 1024, 1024, b1 + 2048, nullptr, mid, nullptr, kBS, 2048, 1024);
  gemm_kernel<7><<<dim3(8, 64), 256, 0, stream>>>(mid, 2048, w2_t + 2048, 4096, nullptr, outp, nullptr, nullptr, kBS, 1024, 2048);
}

// Round 14
// 5334.832 us; speedup vs baseline: 1.0490x; 1.0490x over previous
//
#include <hip/hip_runtime.h>

namespace {

constexpr int kB = 4, kS = 2048, kD = 1024, kH = 16, kF = 4096, kM = 1024;
constexpr int kBS = kB * kS;   // 8192 rows
constexpr int kBM = kB * kM;   // 4096 rows

#define DEV __device__ __forceinline__

DEV float bf2f(unsigned short u){ unsigned int i = ((unsigned int)u) << 16; float f; __builtin_memcpy(&f, &i, 4); return f; }
DEV unsigned short f2bf(float f){ unsigned int i; __builtin_memcpy(&i, &f, 4); return (unsigned short)((i + 0x7fffu + ((i >> 16) & 1u)) >> 16); }
DEV float gelu_f(float x){ float u = 0.7978845608028654f * (x + 0.044715f * x * x * x); return 0.5f * x * (1.0f + tanhf(u)); }
DEV float sigmoid_f(float x){ return 1.0f / (1.0f + __expf(-x)); }
// barrier with LDS-only visibility: no vmcnt(0) drain (outstanding global loads/stores
// survive across it; wave-local uses still get compiler-inserted vmcnt waits)
DEV void softbar(){ asm volatile("s_waitcnt lgkmcnt(0)" ::: "memory"); __builtin_amdgcn_s_barrier(); }

typedef __attribute__((ext_vector_type(8))) short bf16x8;
typedef __attribute__((ext_vector_type(4))) float f32x4;
typedef __attribute__((address_space(1))) const unsigned char gas_u8;
typedef __attribute__((address_space(3))) unsigned char las_u8;

// ---------------- weight transpose (fp32 [K,N] -> bf16 [N,K]) ----------------
__global__ __launch_bounds__(256) void k_transpose_bf16(const float* __restrict__ W, unsigned short* __restrict__ Wt, int K, int N){
  __shared__ float tile[32][33];
  int n0 = blockIdx.x * 32, k0 = blockIdx.y * 32;
  int tx = threadIdx.x, ty = threadIdx.y;
  for (int i = ty; i < 32; i += 8) tile[i][tx] = W[(size_t)(k0 + i) * N + n0 + tx];
  __syncthreads();
  for (int i = ty; i < 32; i += 8) Wt[(size_t)(n0 + i) * K + k0 + tx] = f2bf(tile[tx][i]);
}

// ---------------- rmsnorm (fp32 in -> bf16 out), one row per block ----------------
__global__ __launch_bounds__(256) void k_rmsnorm(const float* __restrict__ x, const float* __restrict__ scale, unsigned short* __restrict__ out){
  int row = blockIdx.x;
  int t = threadIdx.x;
  float4 v = ((const float4*)(x + (size_t)row * kD))[t];
  float ss = v.x*v.x + v.y*v.y + v.z*v.z + v.w*v.w;
  for (int o = 32; o > 0; o >>= 1) ss += __shfl_xor(ss, o);
  __shared__ float red[4];
  int wave = t >> 6, lane = t & 63;
  if (lane == 0) red[wave] = ss;
  __syncthreads();
  float tot = red[0] + red[1] + red[2] + red[3];
  float r = rsqrtf(tot * (1.0f / kD) + 1e-6f);
  float4 s = ((const float4*)scale)[t];
  ushort4 o4;
  o4.x = f2bf(v.x * r * s.x); o4.y = f2bf(v.y * r * s.y);
  o4.z = f2bf(v.z * r * s.z); o4.w = f2bf(v.w * r * s.w);
  *(ushort4*)(out + (size_t)row * kD + t * 4) = o4;
}

// ---------------- fp32 -> bf16 convert ----------------
__global__ __launch_bounds__(256) void k_f32_to_bf16(const float* __restrict__ in, unsigned short* __restrict__ out, int n4){
  int i = blockIdx.x * 256 + threadIdx.x;
  int stride = gridDim.x * 256;
  for (; i < n4; i += stride){
    float4 v = ((const float4*)in)[i];
    ushort4 o; o.x = f2bf(v.x); o.y = f2bf(v.y); o.z = f2bf(v.z); o.w = f2bf(v.w);
    ((ushort4*)out)[i] = o;
  }
}

// ---------------- combine: xres = xres(mem_out) + x + h + 0.1*v ----------------
__global__ __launch_bounds__(256) void k_combine(float* __restrict__ xres, const float* __restrict__ x,
                                                 const float* __restrict__ h, const unsigned short* __restrict__ v, int n4){
  int i = blockIdx.x * 256 + threadIdx.x;
  int stride = gridDim.x * 256;
  for (; i < n4; i += stride){
    float4 a = ((float4*)xres)[i];
    float4 xv = ((const float4*)x)[i];
    float4 hv = ((const float4*)h)[i];
    ushort4 vv = ((const ushort4*)v)[i];
    a.x += xv.x + hv.x + 0.1f * bf2f(vv.x);
    a.y += xv.y + hv.y + 0.1f * bf2f(vv.y);
    a.z += xv.z + hv.z + 0.1f * bf2f(vv.z);
    a.w += xv.w + hv.w + 0.1f * bf2f(vv.w);
    ((float4*)xres)[i] = a;
  }
}

// ---------------- generic bf16 MFMA GEMM: C[M,N] = epi(A[M,K] @ Bt[N,K]^T + bias) ----------------
// EPI: 0 f32 | 1 bf16 | 2 gelu->bf16 | 3 sigmoid->f32 | 4 out1=clip(out1*sigmoid(v)) |
//      5 f32+bf16 dual | 6 out1=src+v | 7 out1+=v | 8 fused qkvz (N=4096, route by n-block) |
//      9 bf16 transposed V-head write: out2 = vhT[b][h][d][key]
template<int EPI>
__global__ __launch_bounds__(256) void gemm_kernel(
    const unsigned short* __restrict__ A, int lda,
    const unsigned short* __restrict__ Bt, int ldb,
    const float* __restrict__ bias,
    float* __restrict__ out1, unsigned short* __restrict__ out2,
    const float* __restrict__ src,
    int Mdim, int Ndim, int Kdim,
    const float* __restrict__ b_k = nullptr,
    const float* __restrict__ b_v = nullptr,
    const float* __restrict__ b_z = nullptr,
    unsigned short* __restrict__ o_k = nullptr,
    unsigned short* __restrict__ o_v = nullptr,
    unsigned short* __restrict__ o_zb = nullptr)
{
  __shared__ unsigned short As[128 * 32];
  __shared__ unsigned short Bs[128 * 32];
  const int t = threadIdx.x;
  const int wave = t >> 6, lane = t & 63;
  const int m0 = blockIdx.y * 128, n0 = blockIdx.x * 128;
  const int wr = (wave >> 1) * 64, wc = (wave & 1) * 64;
  const int lr = lane & 15, lk = lane >> 4;

  f32x4 acc[4][4];
  #pragma unroll
  for (int m = 0; m < 4; ++m)
    #pragma unroll
    for (int n = 0; n < 4; ++n) acc[m][n] = (f32x4){0.f, 0.f, 0.f, 0.f};

  const int r0 = t >> 2, s0 = (t & 3) * 8;
  const int r1 = 64 + r0;
  las_u8* lA0 = (las_u8*)(void*)(As + r0 * 32 + s0);
  las_u8* lA1 = (las_u8*)(void*)(As + r1 * 32 + s0);
  las_u8* lB0 = (las_u8*)(void*)(Bs + r0 * 32 + s0);
  las_u8* lB1 = (las_u8*)(void*)(Bs + r1 * 32 + s0);

  for (int k0 = 0; k0 < Kdim; k0 += 32){
    __syncthreads();
    __builtin_amdgcn_global_load_lds((gas_u8*)(const void*)(A  + (size_t)(m0 + r0) * lda + k0 + s0), lA0, 16, 0, 0);
    __builtin_amdgcn_global_load_lds((gas_u8*)(const void*)(A  + (size_t)(m0 + r1) * lda + k0 + s0), lA1, 16, 0, 0);
    __builtin_amdgcn_global_load_lds((gas_u8*)(const void*)(Bt + (size_t)(n0 + r0) * ldb + k0 + s0), lB0, 16, 0, 0);
    __builtin_amdgcn_global_load_lds((gas_u8*)(const void*)(Bt + (size_t)(n0 + r1) * ldb + k0 + s0), lB1, 16, 0, 0);
    __syncthreads();
    bf16x8 af[4], bfr[4];
    #pragma unroll
    for (int m = 0; m < 4; ++m) af[m] = *(const bf16x8*)(As + (wr + m * 16 + lr) * 32 + lk * 8);
    #pragma unroll
    for (int n = 0; n < 4; ++n) bfr[n] = *(const bf16x8*)(Bs + (wc + n * 16 + lr) * 32 + lk * 8);
    #pragma unroll
    for (int m = 0; m < 4; ++m)
      #pragma unroll
      for (int n = 0; n < 4; ++n)
        acc[m][n] = __builtin_amdgcn_mfma_f32_16x16x32_bf16(af[m], bfr[n], acc[m][n], 0, 0, 0);
  }

  const float* bsel = bias;
  unsigned short* osel = out2;
  int sel = 0;
  if constexpr (EPI == 8){
    sel = n0 >> 10;
    bsel = (sel == 0) ? bias : (sel == 1) ? b_k : (sel == 2) ? b_v : b_z;
    osel = (sel == 0) ? out2 : (sel == 1) ? o_k : (sel == 2) ? o_v : o_zb;
  }

  #pragma unroll
  for (int m = 0; m < 4; ++m){
    #pragma unroll
    for (int n = 0; n < 4; ++n){
      int col = n0 + wc + n * 16 + lr;
      float bv;
      if constexpr (EPI == 8) bv = bsel[col & 1023];
      else bv = bias ? bias[col] : 0.f;
      #pragma unroll
      for (int r = 0; r < 4; ++r){
        int rowg = m0 + wr + m * 16 + lk * 4 + r;
        size_t off = (size_t)rowg * Ndim + col;
        float v = acc[m][n][r] + bv;
        if constexpr (EPI == 0) out1[off] = v;
        else if constexpr (EPI == 1) out2[off] = f2bf(v);
        else if constexpr (EPI == 2) out2[off] = f2bf(gelu_f(v));
        else if constexpr (EPI == 3) out1[off] = sigmoid_f(v);
        else if constexpr (EPI == 4){ float g = out1[off] * sigmoid_f(v); out1[off] = fminf(fmaxf(g, 1e-6f), 1.0f - 1e-6f); }
        else if constexpr (EPI == 5){ out1[off] = v; out2[off] = f2bf(v); }
        else if constexpr (EPI == 6) out1[off] = src[off] + v;
        else if constexpr (EPI == 7) out1[off] += v;
        else if constexpr (EPI == 8){
          size_t off8 = (size_t)rowg * 1024 + (col & 1023);
          if (sel == 3){ out1[off8] = v; osel[off8] = f2bf(v); }
          else osel[off8] = f2bf(v);
        }
        else if constexpr (EPI == 9){
          int bb = rowg >> 10, key = rowg & 1023, hh = col >> 6, dd = col & 63;
          out2[(((size_t)bb * 16 + hh) * 64 + dd) * 1024 + key] = f2bf(v);
        }
      }
    }
  }
}

// ---------------- sequential gated scan (R11 + LDS-only barriers) ----------------
// R11-proven structure: parallel-retry poll, post-poll inputs, 2 barriers, wave0 finalize.
// One change: the two per-step barriers are lgkmcnt(0)+raw s_barrier (no vmcnt(0)
// drain) — cross-wave visibility here is LDS-only (red, hl); wave0's input loads
// and stores keep their compiler-inserted wave-local vmcnt waits. Publish reordered
// before the zh store so it issues one store earlier.
__global__ __launch_bounds__(256) void k_scan(const float* __restrict__ wgh,
                                              const float* __restrict__ gz,
                                              float* __restrict__ zh /* z in, h out (in-place) */,
                                              const float* __restrict__ gamma,
                                              const float* __restrict__ bgh,
                                              unsigned long long* __restrict__ hpub){
  __shared__ unsigned short wsl[1024 * 32]; // [i][col] bf16, 64KB
  __shared__ float hl[1024];
  __shared__ float red[4][32];
  const int t = threadIdx.x;
  const int bid = blockIdx.x;
  const int b = bid & 3, slc = bid >> 2;   // batch-major interleave
  const int colg0 = slc * 32;

  for (int idx = t; idx < 32768; idx += 256){
    int k = idx >> 5, c = idx & 31;
    wsl[idx] = f2bf(wgh[(size_t)k * 1024 + colg0 + c]);
  }
  const float bghv = (t < 32) ? bgh[colg0 + t] : 0.f;
  const int lane = t & 63, w = t >> 6;
  const int lgrp = lane >> 3;
  const int lcol = lane & 7;
  const int ibase = w * 256;
  __syncthreads();

  for (int tt = 0; tt < kS; ++tt){
    if (tt > 0){
      const unsigned want = (unsigned)(tt - 1);
      unsigned long long* pb = hpub + (((size_t)((tt - 1) & 1)) * kB + b) * 1024 + ibase + (lane << 2);
      unsigned long long pv0 = __hip_atomic_load(pb + 0, __ATOMIC_RELAXED, __HIP_MEMORY_SCOPE_AGENT);
      unsigned long long pv1 = __hip_atomic_load(pb + 1, __ATOMIC_RELAXED, __HIP_MEMORY_SCOPE_AGENT);
      unsigned long long pv2 = __hip_atomic_load(pb + 2, __ATOMIC_RELAXED, __HIP_MEMORY_SCOPE_AGENT);
      unsigned long long pv3 = __hip_atomic_load(pb + 3, __ATOMIC_RELAXED, __HIP_MEMORY_SCOPE_AGENT);
      while (true){
        bool ok = ((unsigned)(pv0 >> 32) == want) && ((unsigned)(pv1 >> 32) == want)
               && ((unsigned)(pv2 >> 32) == want) && ((unsigned)(pv3 >> 32) == want);
        if (__all(ok)) break;
        pv0 = __hip_atomic_load(pb + 0, __ATOMIC_RELAXED, __HIP_MEMORY_SCOPE_AGENT);
        pv1 = __hip_atomic_load(pb + 1, __ATOMIC_RELAXED, __HIP_MEMORY_SCOPE_AGENT);
        pv2 = __hip_atomic_load(pb + 2, __ATOMIC_RELAXED, __HIP_MEMORY_SCOPE_AGENT);
        pv3 = __hip_atomic_load(pb + 3, __ATOMIC_RELAXED, __HIP_MEMORY_SCOPE_AGENT);
      }
      int hbase = ibase + (lane << 2);
      hl[hbase + 0] = __uint_as_float((unsigned)pv0);
      hl[hbase + 1] = __uint_as_float((unsigned)pv1);
      hl[hbase + 2] = __uint_as_float((unsigned)pv2);
      hl[hbase + 3] = __uint_as_float((unsigned)pv3);
    } else {
      ((float4*)hl)[t] = make_float4(0.f, 0.f, 0.f, 0.f);
    }
    asm volatile("" ::: "memory");
    float gzv = 0.f, zv = 0.f, gv = 0.f;
    size_t inidx = 0;
    if (t < 32){
      inidx = ((size_t)b * kS + tt) * 1024 + colg0 + t;
      gzv = gz[inidx]; zv = zh[inidx]; gv = gamma[inidx];
    }

    float a0 = 0.f, a1 = 0.f, a2 = 0.f, a3 = 0.f;
    const unsigned short* wb = wsl + ibase * 32;
    #pragma unroll 4
    for (int j = 0; j < 32; ++j){
      int i = j * 8 + lgrp;
      float hv = hl[ibase + i];
      uint2 ww = *(const uint2*)(wb + i * 32 + lcol * 4);
      a0 += hv * bf2f((unsigned short)(ww.x & 0xffffu));
      a1 += hv * bf2f((unsigned short)(ww.x >> 16));
      a2 += hv * bf2f((unsigned short)(ww.y & 0xffffu));
      a3 += hv * bf2f((unsigned short)(ww.y >> 16));
    }
    for (int o = 8; o < 64; o <<= 1){
      a0 += __shfl_xor(a0, o); a1 += __shfl_xor(a1, o);
      a2 += __shfl_xor(a2, o); a3 += __shfl_xor(a3, o);
    }
    if (lane < 8){
      red[w][lane * 4 + 0] = a0; red[w][lane * 4 + 1] = a1;
      red[w][lane * 4 + 2] = a2; red[w][lane * 4 + 3] = a3;
    }
    softbar();   // LDS-visibility barrier: no vmcnt drain of wave0's input loads

    if (t < 32){
      float sum = red[0][t] + red[1][t] + red[2][t] + red[3][t];
      float gate = sigmoid_f(gzv + sum + bghv);
      float hp = hl[colg0 + t];
      float ht = (1.0f - gate) * hp + gate * zv + gv * hp;
      ht = fminf(fmaxf(ht, -100.0f), 100.0f);
      unsigned long long pv = ((unsigned long long)(unsigned)tt << 32)
                            | (unsigned long long)__float_as_uint(ht);
      __hip_atomic_store(hpub + (((size_t)(tt & 1)) * kB + b) * 1024 + colg0 + t, pv,
                         __ATOMIC_RELAXED, __HIP_MEMORY_SCOPE_AGENT);
      zh[inidx] = ht;   // plain store; consumed after kernel end
    }
    softbar();   // protects red/hl WAR for next iteration (LDS-only)
  }
}

// ---------------- MFMA flash attention: block = (64 q-rows, h, b); 4 waves x 16 rows ----------------
__global__ __launch_bounds__(256) void k_attn_mfma(const unsigned short* __restrict__ q,
                                                   const unsigned short* __restrict__ kh,
                                                   const unsigned short* __restrict__ vhT,
                                                   unsigned short* __restrict__ ao){
  __shared__ unsigned short Qs[2][64][32];
  __shared__ unsigned short Ks[2][128][32];
  __shared__ unsigned short Vt[4][64][32];
  __shared__ unsigned short Ps[4][4][16][32];
  const int t = threadIdx.x;
  const int qt = blockIdx.x, h = blockIdx.y, b = blockIdx.z;
  const int lane = t & 63, w = t >> 6;
  const int lk = lane >> 4, lr = lane & 15;

  for (int i = t; i < 512; i += 256){
    int row = i >> 3, cg = (i & 7) * 8;
    *(uint4*)&Qs[cg >> 5][row][cg & 31] =
      *(const uint4*)(q + ((size_t)(b * kS + qt * 64 + row)) * kD + h * 64 + cg);
  }

  f32x4 acc_o[4];
  #pragma unroll
  for (int n = 0; n < 4; ++n) acc_o[n] = (f32x4){0.f, 0.f, 0.f, 0.f};
  float m_[4], l_[4];
  #pragma unroll
  for (int r = 0; r < 4; ++r){ m_[r] = -3e38f; l_[r] = 0.f; }

  for (int c = 0; c < 8; ++c){
    __syncthreads();
    for (int i = t; i < 1024; i += 256){
      int key = i >> 3, cg = (i & 7) * 8;
      *(uint4*)&Ks[cg >> 5][key][cg & 31] =
        *(const uint4*)(kh + ((size_t)(b * kM + c * 128 + key)) * kD + h * 64 + cg);
    }
    for (int i = t; i < 1024; i += 256){
      int d = i >> 4, kg = (i & 15) * 8;
      *(uint4*)&Vt[kg >> 5][d][kg & 31] =
        *(const uint4*)(vhT + (((size_t)(b * 16 + h)) * 64 + d) * 1024 + c * 128 + kg);
    }
    __syncthreads();

    f32x4 accs[8];
    #pragma unroll
    for (int n = 0; n < 8; ++n) accs[n] = (f32x4){0.f, 0.f, 0.f, 0.f};
    #pragma unroll
    for (int kk = 0; kk < 2; ++kk){
      bf16x8 aq = *(const bf16x8*)&Qs[kk][16 * w + lr][lk * 8];
      #pragma unroll
      for (int n = 0; n < 8; ++n){
        bf16x8 bk8 = *(const bf16x8*)&Ks[kk][16 * n + lr][lk * 8];
        accs[n] = __builtin_amdgcn_mfma_f32_16x16x32_bf16(aq, bk8, accs[n], 0, 0, 0);
      }
    }

    #pragma unroll
    for (int n = 0; n < 8; ++n)
      #pragma unroll
      for (int r = 0; r < 4; ++r) accs[n][r] *= 0.125f;
    float mnew[4], alpha[4], psum[4];
    #pragma unroll
    for (int r = 0; r < 4; ++r){
      float mx = accs[0][r];
      #pragma unroll
      for (int n = 1; n < 8; ++n) mx = fmaxf(mx, accs[n][r]);
      #pragma unroll
      for (int o = 1; o < 16; o <<= 1) mx = fmaxf(mx, __shfl_xor(mx, o));
      mnew[r] = fmaxf(m_[r], mx);
      alpha[r] = __expf(m_[r] - mnew[r]);
      m_[r] = mnew[r];
      psum[r] = 0.f;
    }
    #pragma unroll
    for (int n = 0; n < 8; ++n){
      #pragma unroll
      for (int r = 0; r < 4; ++r){
        float p = __expf(accs[n][r] - mnew[r]);
        psum[r] += p;
        Ps[w][n >> 1][lk * 4 + r][16 * (n & 1) + lr] = f2bf(p);
      }
    }
    #pragma unroll
    for (int r = 0; r < 4; ++r){
      float s = psum[r];
      #pragma unroll
      for (int o = 1; o < 16; o <<= 1) s += __shfl_xor(s, o);
      l_[r] = l_[r] * alpha[r] + s;
      #pragma unroll
      for (int n = 0; n < 4; ++n) acc_o[n][r] *= alpha[r];
    }

    #pragma unroll
    for (int kk = 0; kk < 4; ++kk){
      bf16x8 ap = *(const bf16x8*)&Ps[w][kk][lr][lk * 8];
      #pragma unroll
      for (int n = 0; n < 4; ++n){
        bf16x8 bv8 = *(const bf16x8*)&Vt[kk][16 * n + lr][lk * 8];
        acc_o[n] = __builtin_amdgcn_mfma_f32_16x16x32_bf16(ap, bv8, acc_o[n], 0, 0, 0);
      }
    }
  }

  #pragma unroll
  for (int n = 0; n < 4; ++n){
    #pragma unroll
    for (int r = 0; r < 4; ++r){
      size_t off = ((size_t)(b * kS + qt * 64 + 16 * w + lk * 4 + r)) * kD + h * 64 + 16 * n + lr;
      ao[off] = f2bf(acc_o[n][r] / l_[r]);
    }
  }
}

} // namespace

extern "C" void kernel_launch(void* const* d_in, const int* in_sizes, int n_in,
                              void* d_out, int out_size, void* d_ws, size_t ws_size,
                              hipStream_t stream){
  (void)in_sizes; (void)n_in; (void)out_size;
  const float* x    = (const float*)d_in[0];
  const float* memk = (const float*)d_in[1];
  const float* memv = (const float*)d_in[2];
  const float* n1   = (const float*)d_in[3];
  const float* n2   = (const float*)d_in[4];
  const float* wq   = (const float*)d_in[5];   const float* bq  = (const float*)d_in[6];
  const float* wk   = (const float*)d_in[7];   const float* bk  = (const float*)d_in[8];
  const float* wv   = (const float*)d_in[9];   const float* bv  = (const float*)d_in[10];
  const float* wz   = (const float*)d_in[11];  const float* bz  = (const float*)d_in[12];
  const float* wgz  = (const float*)d_in[13];  const float* bgz = (const float*)d_in[14];
  const float* wgh  = (const float*)d_in[15];  const float* bgh = (const float*)d_in[16];
  const float* wg1  = (const float*)d_in[17];  const float* bg1 = (const float*)d_in[18];
  const float* wg2  = (const float*)d_in[19];  const float* bg2 = (const float*)d_in[20];
  const float* wc1  = (const float*)d_in[21];  const float* bc1 = (const float*)d_in[22];
  const float* wc2  = (const float*)d_in[23];  const float* bc2 = (const float*)d_in[24];
  const float* wak  = (const float*)d_in[25];  const float* bak = (const float*)d_in[26];
  const float* wav  = (const float*)d_in[27];  const float* bav = (const float*)d_in[28];
  const float* wao  = (const float*)d_in[29];  const float* bao = (const float*)d_in[30];
  const float* w1   = (const float*)d_in[31];  const float* b1  = (const float*)d_in[32];
  const float* w2   = (const float*)d_in[33];  const float* b2  = (const float*)d_in[34];
  float* outp = (float*)d_out;
  char* ws = (char*)d_ws;
  const size_t MBy = 1024ull * 1024ull;
  if (ws_size < 252 * MBy) return; // need 252MB scratch

  // ---- workspace layout (time-multiplexed regions) ----
  unsigned short* wq_t  = (unsigned short*)(ws + 0 * MBy);   // wq/wk/wv/wz contiguous: fused N=4096 Bt
  unsigned short* wk_t  = (unsigned short*)(ws + 2 * MBy);
  unsigned short* wv_t  = (unsigned short*)(ws + 4 * MBy);
  unsigned short* wz_t  = (unsigned short*)(ws + 6 * MBy);
  unsigned short* wgz_t = (unsigned short*)(ws + 8 * MBy);
  unsigned short* wak_t = (unsigned short*)(ws + 10 * MBy);
  unsigned short* wav_t = (unsigned short*)(ws + 12 * MBy);
  unsigned short* wao_t = (unsigned short*)(ws + 14 * MBy);
  unsigned short* wg1_t = (unsigned short*)(ws + 16 * MBy);
  unsigned short* wg2_t = (unsigned short*)(ws + 16 * MBy + 524288);
  unsigned short* wc1_t = (unsigned short*)(ws + 16 * MBy + 2 * 524288);
  unsigned short* wc2_t = (unsigned short*)(ws + 16 * MBy + 3 * 524288);
  unsigned short* w1_t  = (unsigned short*)(ws + 18 * MBy);
  unsigned short* w2_t  = (unsigned short*)(ws + 26 * MBy);
  unsigned long long* hpub = (unsigned long long*)(ws + 34 * MBy); // 64KB
  unsigned short* xn    = (unsigned short*)(ws + 40 * MBy);
  unsigned short* memk_b= (unsigned short*)(ws + 40 * MBy);
  unsigned short* memv_b= (unsigned short*)(ws + 48 * MBy);
  unsigned short* ao    = (unsigned short*)(ws + 40 * MBy);   // after kh/vhT GEMMs consume memk_b/memv_b
  unsigned short* qb_   = (unsigned short*)(ws + 56 * MBy);
  unsigned short* xn2   = (unsigned short*)(ws + 56 * MBy);
  unsigned short* kb_   = (unsigned short*)(ws + 72 * MBy);
  unsigned short* khb   = (unsigned short*)(ws + 72 * MBy);
  unsigned short* vhT   = (unsigned short*)(ws + 80 * MBy);   // [b][h][d][key] 8MB
  unsigned short* vb_   = (unsigned short*)(ws + 88 * MBy);
  float*          zf    = (float*)(ws + 104 * MBy);
  unsigned short* zb_   = (unsigned short*)(ws + 136 * MBy);
  unsigned short* mid   = (unsigned short*)(ws + 136 * MBy);
  float*          gzf   = (float*)(ws + 152 * MBy);
  float*          gmf   = (float*)(ws + 184 * MBy);
  unsigned short* g1b   = (unsigned short*)(ws + 216 * MBy);
  float*          xres  = (float*)(ws + 220 * MBy);

  dim3 tb(32, 8);
  // ---- weight transposes (wgh consumed directly by k_scan) ----
  k_transpose_bf16<<<dim3(32, 32), tb, 0, stream>>>(wq,  wq_t,  1024, 1024);
  k_transpose_bf16<<<dim3(32, 32), tb, 0, stream>>>(wk,  wk_t,  1024, 1024);
  k_transpose_bf16<<<dim3(32, 32), tb, 0, stream>>>(wv,  wv_t,  1024, 1024);
  k_transpose_bf16<<<dim3(32, 32), tb, 0, stream>>>(wz,  wz_t,  1024, 1024);
  k_transpose_bf16<<<dim3(32, 32), tb, 0, stream>>>(wgz, wgz_t, 1024, 1024);
  k_transpose_bf16<<<dim3(32, 32), tb, 0, stream>>>(wak, wak_t, 1024, 1024);
  k_transpose_bf16<<<dim3(32, 32), tb, 0, stream>>>(wav, wav_t, 1024, 1024);
  k_transpose_bf16<<<dim3(32, 32), tb, 0, stream>>>(wao, wao_t, 1024, 1024);
  k_transpose_bf16<<<dim3(8, 32),  tb, 0, stream>>>(wg1, wg1_t, 1024, 256);
  k_transpose_bf16<<<dim3(32, 8),  tb, 0, stream>>>(wg2, wg2_t, 256, 1024);
  k_transpose_bf16<<<dim3(8, 32),  tb, 0, stream>>>(wc1, wc1_t, 1024, 256);
  k_transpose_bf16<<<dim3(32, 8),  tb, 0, stream>>>(wc2, wc2_t, 256, 1024);
  k_transpose_bf16<<<dim3(128, 32),tb, 0, stream>>>(w1,  w1_t,  1024, 4096);
  k_transpose_bf16<<<dim3(32, 128),tb, 0, stream>>>(w2,  w2_t,  4096, 1024);

  // ---- norm + fused q/k/v/z projection ----
  k_rmsnorm<<<kBS, 256, 0, stream>>>(x, n1, xn);
  gemm_kernel<8><<<dim3(32, 64), 256, 0, stream>>>(xn, 1024, wq_t, 1024, bq, zf, qb_, nullptr,
                                                   kBS, 4096, 1024, bk, bv, bz, kb_, vb_, zb_);

  // ---- gate_z_seq and gamma ----
  gemm_kernel<0><<<dim3(8, 64), 256, 0, stream>>>(zb_, 1024, wgz_t, 1024, bgz, gzf, nullptr, nullptr, kBS, 1024, 1024);
  gemm_kernel<2><<<dim3(2, 64), 256, 0, stream>>>(zb_, 1024, wg1_t, 1024, bg1, nullptr, g1b, nullptr, kBS, 256, 1024);
  gemm_kernel<3><<<dim3(8, 64), 256, 0, stream>>>(g1b, 256, wg2_t, 256, bg2, gmf, nullptr, nullptr, kBS, 1024, 256);
  gemm_kernel<2><<<dim3(2, 64), 256, 0, stream>>>(kb_, 1024, wc1_t, 1024, bc1, nullptr, g1b, nullptr, kBS, 256, 1024);
  gemm_kernel<4><<<dim3(8, 64), 256, 0, stream>>>(g1b, 256, wc2_t, 256, bc2, gmf, nullptr, nullptr, kBS, 1024, 256);

  // ---- sequential scan (h written in-place over z; hpub re-tagged each launch) ----
  hipMemsetAsync(hpub, 0xFF, 65536, stream);
  k_scan<<<128, 256, 0, stream>>>(wgh, gzf, zf, gmf, bgh, hpub);

  // ---- memory attention (MFMA flash; V written transposed by EPI 9) ----
  k_f32_to_bf16<<<1024, 256, 0, stream>>>(memk, memk_b, kBM * kD / 4);
  k_f32_to_bf16<<<1024, 256, 0, stream>>>(memv, memv_b, kBM * kD / 4);
  gemm_kernel<1><<<dim3(8, 32), 256, 0, stream>>>(memk_b, 1024, wak_t, 1024, bak, nullptr, khb, nullptr, kBM, 1024, 1024);
  gemm_kernel<9><<<dim3(8, 32), 256, 0, stream>>>(memv_b, 1024, wav_t, 1024, bav, nullptr, vhT, nullptr, kBM, 1024, 1024);
  k_attn_mfma<<<dim3(32, 16, 4), 256, 0, stream>>>(qb_, khb, vhT, ao);
  gemm_kernel<0><<<dim3(8, 64), 256, 0, stream>>>(ao, 1024, wao_t, 1024, bao, xres, nullptr, nullptr, kBS, 1024, 1024);

  // ---- combine + norm2 + FFN (F split in two 2048 chunks to bound scratch) ----
  k_combine<<<2048, 256, 0, stream>>>(xres, x, zf, vb_, kBS * kD / 4);
  k_rmsnorm<<<kBS, 256, 0, stream>>>(xres, n2, xn2);
  gemm_kernel<2><<<dim3(16, 64), 256, 0, stream>>>(xn2, 1024, w1_t, 1024, b1, nullptr, mid, nullptr, kBS, 2048, 1024);
  gemm_kernel<6><<<dim3(8, 64), 256, 0, stream>>>(mid, 2048, w2_t, 4096, b2, outp, nullptr, xres, kBS, 1024, 2048);
  gemm_kernel<2><<<dim3(16, 64), 256, 0, stream>>>(xn2, 1024, w1_t + (size_t)2048 * 1024, 1024, b1 + 2048, nullptr, mid, nullptr, kBS, 2048, 1024);
  gemm_kernel<7><<<dim3(8, 64), 256, 0, stream>>>(mid, 2048, w2_t + 2048, 4096, nullptr, outp, nullptr, nullptr, kBS, 1024, 2048);
}

// Round 15
// 5212.803 us; speedup vs baseline: 1.0736x; 1.0234x over previous
//
#include <hip/hip_runtime.h>

namespace {

constexpr int kB = 4, kS = 2048, kD = 1024, kH = 16, kF = 4096, kM = 1024;
constexpr int kBS = kB * kS;   // 8192 rows
constexpr int kBM = kB * kM;   // 4096 rows

#define DEV __device__ __forceinline__

DEV float bf2f(unsigned short u){ unsigned int i = ((unsigned int)u) << 16; float f; __builtin_memcpy(&f, &i, 4); return f; }
DEV unsigned short f2bf(float f){ unsigned int i; __builtin_memcpy(&i, &f, 4); return (unsigned short)((i + 0x7fffu + ((i >> 16) & 1u)) >> 16); }
DEV float gelu_f(float x){ float u = 0.7978845608028654f * (x + 0.044715f * x * x * x); return 0.5f * x * (1.0f + tanhf(u)); }
DEV float sigmoid_f(float x){ return 1.0f / (1.0f + __expf(-x)); }

typedef __attribute__((ext_vector_type(8))) short bf16x8;
typedef __attribute__((ext_vector_type(4))) float f32x4;
typedef __attribute__((address_space(1))) const unsigned char gas_u8;
typedef __attribute__((address_space(3))) unsigned char las_u8;

// ---------------- weight transpose (fp32 [K,N] -> bf16 [N,K]) ----------------
__global__ __launch_bounds__(256) void k_transpose_bf16(const float* __restrict__ W, unsigned short* __restrict__ Wt, int K, int N){
  __shared__ float tile[32][33];
  int n0 = blockIdx.x * 32, k0 = blockIdx.y * 32;
  int tx = threadIdx.x, ty = threadIdx.y;
  for (int i = ty; i < 32; i += 8) tile[i][tx] = W[(size_t)(k0 + i) * N + n0 + tx];
  __syncthreads();
  for (int i = ty; i < 32; i += 8) Wt[(size_t)(n0 + i) * K + k0 + tx] = f2bf(tile[tx][i]);
}

// ---------------- rmsnorm (fp32 in -> bf16 out), one row per block ----------------
__global__ __launch_bounds__(256) void k_rmsnorm(const float* __restrict__ x, const float* __restrict__ scale, unsigned short* __restrict__ out){
  int row = blockIdx.x;
  int t = threadIdx.x;
  float4 v = ((const float4*)(x + (size_t)row * kD))[t];
  float ss = v.x*v.x + v.y*v.y + v.z*v.z + v.w*v.w;
  for (int o = 32; o > 0; o >>= 1) ss += __shfl_xor(ss, o);
  __shared__ float red[4];
  int wave = t >> 6, lane = t & 63;
  if (lane == 0) red[wave] = ss;
  __syncthreads();
  float tot = red[0] + red[1] + red[2] + red[3];
  float r = rsqrtf(tot * (1.0f / kD) + 1e-6f);
  float4 s = ((const float4*)scale)[t];
  ushort4 o4;
  o4.x = f2bf(v.x * r * s.x); o4.y = f2bf(v.y * r * s.y);
  o4.z = f2bf(v.z * r * s.z); o4.w = f2bf(v.w * r * s.w);
  *(ushort4*)(out + (size_t)row * kD + t * 4) = o4;
}

// ---------------- fp32 -> bf16 convert ----------------
__global__ __launch_bounds__(256) void k_f32_to_bf16(const float* __restrict__ in, unsigned short* __restrict__ out, int n4){
  int i = blockIdx.x * 256 + threadIdx.x;
  int stride = gridDim.x * 256;
  for (; i < n4; i += stride){
    float4 v = ((const float4*)in)[i];
    ushort4 o; o.x = f2bf(v.x); o.y = f2bf(v.y); o.z = f2bf(v.z); o.w = f2bf(v.w);
    ((ushort4*)out)[i] = o;
  }
}

// ---------------- combine: xres = xres(mem_out) + x + h + 0.1*v ----------------
__global__ __launch_bounds__(256) void k_combine(float* __restrict__ xres, const float* __restrict__ x,
                                                 const float* __restrict__ h, const unsigned short* __restrict__ v, int n4){
  int i = blockIdx.x * 256 + threadIdx.x;
  int stride = gridDim.x * 256;
  for (; i < n4; i += stride){
    float4 a = ((float4*)xres)[i];
    float4 xv = ((const float4*)x)[i];
    float4 hv = ((const float4*)h)[i];
    ushort4 vv = ((const ushort4*)v)[i];
    a.x += xv.x + hv.x + 0.1f * bf2f(vv.x);
    a.y += xv.y + hv.y + 0.1f * bf2f(vv.y);
    a.z += xv.z + hv.z + 0.1f * bf2f(vv.z);
    a.w += xv.w + hv.w + 0.1f * bf2f(vv.w);
    ((float4*)xres)[i] = a;
  }
}

// ---------------- generic bf16 MFMA GEMM: C[M,N] = epi(A[M,K] @ Bt[N,K]^T + bias) ----------------
// EPI: 0 f32 | 1 bf16 | 2 gelu->bf16 | 3 sigmoid->f32 | 4 out1=clip(out1*sigmoid(v)) |
//      5 f32+bf16 dual | 6 out1=src+v | 7 out1+=v | 8 fused qkvz (N=4096, route by n-block) |
//      9 bf16 transposed V-head write: out2 = vhT[b][h][d][key]
template<int EPI>
__global__ __launch_bounds__(256) void gemm_kernel(
    const unsigned short* __restrict__ A, int lda,
    const unsigned short* __restrict__ Bt, int ldb,
    const float* __restrict__ bias,
    float* __restrict__ out1, unsigned short* __restrict__ out2,
    const float* __restrict__ src,
    int Mdim, int Ndim, int Kdim,
    const float* __restrict__ b_k = nullptr,
    const float* __restrict__ b_v = nullptr,
    const float* __restrict__ b_z = nullptr,
    unsigned short* __restrict__ o_k = nullptr,
    unsigned short* __restrict__ o_v = nullptr,
    unsigned short* __restrict__ o_zb = nullptr)
{
  __shared__ unsigned short As[128 * 32];
  __shared__ unsigned short Bs[128 * 32];
  const int t = threadIdx.x;
  const int wave = t >> 6, lane = t & 63;
  const int m0 = blockIdx.y * 128, n0 = blockIdx.x * 128;
  const int wr = (wave >> 1) * 64, wc = (wave & 1) * 64;
  const int lr = lane & 15, lk = lane >> 4;

  f32x4 acc[4][4];
  #pragma unroll
  for (int m = 0; m < 4; ++m)
    #pragma unroll
    for (int n = 0; n < 4; ++n) acc[m][n] = (f32x4){0.f, 0.f, 0.f, 0.f};

  const int r0 = t >> 2, s0 = (t & 3) * 8;
  const int r1 = 64 + r0;
  las_u8* lA0 = (las_u8*)(void*)(As + r0 * 32 + s0);
  las_u8* lA1 = (las_u8*)(void*)(As + r1 * 32 + s0);
  las_u8* lB0 = (las_u8*)(void*)(Bs + r0 * 32 + s0);
  las_u8* lB1 = (las_u8*)(void*)(Bs + r1 * 32 + s0);

  for (int k0 = 0; k0 < Kdim; k0 += 32){
    __syncthreads();
    __builtin_amdgcn_global_load_lds((gas_u8*)(const void*)(A  + (size_t)(m0 + r0) * lda + k0 + s0), lA0, 16, 0, 0);
    __builtin_amdgcn_global_load_lds((gas_u8*)(const void*)(A  + (size_t)(m0 + r1) * lda + k0 + s0), lA1, 16, 0, 0);
    __builtin_amdgcn_global_load_lds((gas_u8*)(const void*)(Bt + (size_t)(n0 + r0) * ldb + k0 + s0), lB0, 16, 0, 0);
    __builtin_amdgcn_global_load_lds((gas_u8*)(const void*)(Bt + (size_t)(n0 + r1) * ldb + k0 + s0), lB1, 16, 0, 0);
    __syncthreads();
    bf16x8 af[4], bfr[4];
    #pragma unroll
    for (int m = 0; m < 4; ++m) af[m] = *(const bf16x8*)(As + (wr + m * 16 + lr) * 32 + lk * 8);
    #pragma unroll
    for (int n = 0; n < 4; ++n) bfr[n] = *(const bf16x8*)(Bs + (wc + n * 16 + lr) * 32 + lk * 8);
    #pragma unroll
    for (int m = 0; m < 4; ++m)
      #pragma unroll
      for (int n = 0; n < 4; ++n)
        acc[m][n] = __builtin_amdgcn_mfma_f32_16x16x32_bf16(af[m], bfr[n], acc[m][n], 0, 0, 0);
  }

  const float* bsel = bias;
  unsigned short* osel = out2;
  int sel = 0;
  if constexpr (EPI == 8){
    sel = n0 >> 10;
    bsel = (sel == 0) ? bias : (sel == 1) ? b_k : (sel == 2) ? b_v : b_z;
    osel = (sel == 0) ? out2 : (sel == 1) ? o_k : (sel == 2) ? o_v : o_zb;
  }

  #pragma unroll
  for (int m = 0; m < 4; ++m){
    #pragma unroll
    for (int n = 0; n < 4; ++n){
      int col = n0 + wc + n * 16 + lr;
      float bv;
      if constexpr (EPI == 8) bv = bsel[col & 1023];
      else bv = bias ? bias[col] : 0.f;
      #pragma unroll
      for (int r = 0; r < 4; ++r){
        int rowg = m0 + wr + m * 16 + lk * 4 + r;
        size_t off = (size_t)rowg * Ndim + col;
        float v = acc[m][n][r] + bv;
        if constexpr (EPI == 0) out1[off] = v;
        else if constexpr (EPI == 1) out2[off] = f2bf(v);
        else if constexpr (EPI == 2) out2[off] = f2bf(gelu_f(v));
        else if constexpr (EPI == 3) out1[off] = sigmoid_f(v);
        else if constexpr (EPI == 4){ float g = out1[off] * sigmoid_f(v); out1[off] = fminf(fmaxf(g, 1e-6f), 1.0f - 1e-6f); }
        else if constexpr (EPI == 5){ out1[off] = v; out2[off] = f2bf(v); }
        else if constexpr (EPI == 6) out1[off] = src[off] + v;
        else if constexpr (EPI == 7) out1[off] += v;
        else if constexpr (EPI == 8){
          size_t off8 = (size_t)rowg * 1024 + (col & 1023);
          if (sel == 3){ out1[off8] = v; osel[off8] = f2bf(v); }
          else osel[off8] = f2bf(v);
        }
        else if constexpr (EPI == 9){
          int bb = rowg >> 10, key = rowg & 1023, hh = col >> 6, dd = col & 63;
          out2[(((size_t)bb * 16 + hh) * 64 + dd) * 1024 + key] = f2bf(v);
        }
      }
    }
  }
}

// ---------------- sequential gated scan (R11: parallel-retry poll + post-poll inputs) ----------------
__global__ __launch_bounds__(256) void k_scan(const float* __restrict__ wgh,
                                              const float* __restrict__ gz,
                                              float* __restrict__ zh /* z in, h out (in-place) */,
                                              const float* __restrict__ gamma,
                                              const float* __restrict__ bgh,
                                              unsigned long long* __restrict__ hpub){
  __shared__ unsigned short wsl[1024 * 32]; // [i][col] bf16, 64KB
  __shared__ float hl[1024];
  __shared__ float red[4][32];
  const int t = threadIdx.x;
  const int bid = blockIdx.x;
  const int b = bid & 3, slc = bid >> 2;   // batch-major interleave
  const int colg0 = slc * 32;

  for (int idx = t; idx < 32768; idx += 256){
    int k = idx >> 5, c = idx & 31;
    wsl[idx] = f2bf(wgh[(size_t)k * 1024 + colg0 + c]);
  }
  const float bghv = (t < 32) ? bgh[colg0 + t] : 0.f;
  const int lane = t & 63, w = t >> 6;
  const int lgrp = lane >> 3;
  const int lcol = lane & 7;
  const int ibase = w * 256;
  __syncthreads();

  for (int tt = 0; tt < kS; ++tt){
    if (tt > 0){
      const unsigned want = (unsigned)(tt - 1);
      unsigned long long* pb = hpub + (((size_t)((tt - 1) & 1)) * kB + b) * 1024 + ibase + (lane << 2);
      unsigned long long pv0 = __hip_atomic_load(pb + 0, __ATOMIC_RELAXED, __HIP_MEMORY_SCOPE_AGENT);
      unsigned long long pv1 = __hip_atomic_load(pb + 1, __ATOMIC_RELAXED, __HIP_MEMORY_SCOPE_AGENT);
      unsigned long long pv2 = __hip_atomic_load(pb + 2, __ATOMIC_RELAXED, __HIP_MEMORY_SCOPE_AGENT);
      unsigned long long pv3 = __hip_atomic_load(pb + 3, __ATOMIC_RELAXED, __HIP_MEMORY_SCOPE_AGENT);
      while (true){
        bool ok = ((unsigned)(pv0 >> 32) == want) && ((unsigned)(pv1 >> 32) == want)
               && ((unsigned)(pv2 >> 32) == want) && ((unsigned)(pv3 >> 32) == want);
        if (__all(ok)) break;
        pv0 = __hip_atomic_load(pb + 0, __ATOMIC_RELAXED, __HIP_MEMORY_SCOPE_AGENT);
        pv1 = __hip_atomic_load(pb + 1, __ATOMIC_RELAXED, __HIP_MEMORY_SCOPE_AGENT);
        pv2 = __hip_atomic_load(pb + 2, __ATOMIC_RELAXED, __HIP_MEMORY_SCOPE_AGENT);
        pv3 = __hip_atomic_load(pb + 3, __ATOMIC_RELAXED, __HIP_MEMORY_SCOPE_AGENT);
      }
      int hbase = ibase + (lane << 2);
      hl[hbase + 0] = __uint_as_float((unsigned)pv0);
      hl[hbase + 1] = __uint_as_float((unsigned)pv1);
      hl[hbase + 2] = __uint_as_float((unsigned)pv2);
      hl[hbase + 3] = __uint_as_float((unsigned)pv3);
    } else {
      ((float4*)hl)[t] = make_float4(0.f, 0.f, 0.f, 0.f);
    }
    asm volatile("" ::: "memory");
    float gzv = 0.f, zv = 0.f, gv = 0.f;
    size_t inidx = 0;
    if (t < 32){
      inidx = ((size_t)b * kS + tt) * 1024 + colg0 + t;
      gzv = gz[inidx]; zv = zh[inidx]; gv = gamma[inidx];
    }

    float a0 = 0.f, a1 = 0.f, a2 = 0.f, a3 = 0.f;
    const unsigned short* wb = wsl + ibase * 32;
    #pragma unroll 4
    for (int j = 0; j < 32; ++j){
      int i = j * 8 + lgrp;
      float hv = hl[ibase + i];
      uint2 ww = *(const uint2*)(wb + i * 32 + lcol * 4);
      a0 += hv * bf2f((unsigned short)(ww.x & 0xffffu));
      a1 += hv * bf2f((unsigned short)(ww.x >> 16));
      a2 += hv * bf2f((unsigned short)(ww.y & 0xffffu));
      a3 += hv * bf2f((unsigned short)(ww.y >> 16));
    }
    for (int o = 8; o < 64; o <<= 1){
      a0 += __shfl_xor(a0, o); a1 += __shfl_xor(a1, o);
      a2 += __shfl_xor(a2, o); a3 += __shfl_xor(a3, o);
    }
    if (lane < 8){
      red[w][lane * 4 + 0] = a0; red[w][lane * 4 + 1] = a1;
      red[w][lane * 4 + 2] = a2; red[w][lane * 4 + 3] = a3;
    }
    __syncthreads();

    if (t < 32){
      float sum = red[0][t] + red[1][t] + red[2][t] + red[3][t];
      float gate = sigmoid_f(gzv + sum + bghv);
      float hp = hl[colg0 + t];
      float ht = (1.0f - gate) * hp + gate * zv + gv * hp;
      ht = fminf(fmaxf(ht, -100.0f), 100.0f);
      zh[inidx] = ht;
      unsigned long long pv = ((unsigned long long)(unsigned)tt << 32)
                            | (unsigned long long)__float_as_uint(ht);
      __hip_atomic_store(hpub + (((size_t)(tt & 1)) * kB + b) * 1024 + colg0 + t, pv,
                         __ATOMIC_RELAXED, __HIP_MEMORY_SCOPE_AGENT);
    }
    __syncthreads();
  }
}

// ---------------- MFMA flash attention: block = (64 q-rows, h, b); 4 waves x 16 rows ----------------
__global__ __launch_bounds__(256) void k_attn_mfma(const unsigned short* __restrict__ q,
                                                   const unsigned short* __restrict__ kh,
                                                   const unsigned short* __restrict__ vhT,
                                                   unsigned short* __restrict__ ao){
  __shared__ unsigned short Qs[2][64][32];
  __shared__ unsigned short Ks[2][128][32];
  __shared__ unsigned short Vt[4][64][32];
  __shared__ unsigned short Ps[4][4][16][32];
  const int t = threadIdx.x;
  const int qt = blockIdx.x, h = blockIdx.y, b = blockIdx.z;
  const int lane = t & 63, w = t >> 6;
  const int lk = lane >> 4, lr = lane & 15;

  for (int i = t; i < 512; i += 256){
    int row = i >> 3, cg = (i & 7) * 8;
    *(uint4*)&Qs[cg >> 5][row][cg & 31] =
      *(const uint4*)(q + ((size_t)(b * kS + qt * 64 + row)) * kD + h * 64 + cg);
  }

  f32x4 acc_o[4];
  #pragma unroll
  for (int n = 0; n < 4; ++n) acc_o[n] = (f32x4){0.f, 0.f, 0.f, 0.f};
  float m_[4], l_[4];
  #pragma unroll
  for (int r = 0; r < 4; ++r){ m_[r] = -3e38f; l_[r] = 0.f; }

  for (int c = 0; c < 8; ++c){
    __syncthreads();
    for (int i = t; i < 1024; i += 256){
      int key = i >> 3, cg = (i & 7) * 8;
      *(uint4*)&Ks[cg >> 5][key][cg & 31] =
        *(const uint4*)(kh + ((size_t)(b * kM + c * 128 + key)) * kD + h * 64 + cg);
    }
    for (int i = t; i < 1024; i += 256){
      int d = i >> 4, kg = (i & 15) * 8;
      *(uint4*)&Vt[kg >> 5][d][kg & 31] =
        *(const uint4*)(vhT + (((size_t)(b * 16 + h)) * 64 + d) * 1024 + c * 128 + kg);
    }
    __syncthreads();

    f32x4 accs[8];
    #pragma unroll
    for (int n = 0; n < 8; ++n) accs[n] = (f32x4){0.f, 0.f, 0.f, 0.f};
    #pragma unroll
    for (int kk = 0; kk < 2; ++kk){
      bf16x8 aq = *(const bf16x8*)&Qs[kk][16 * w + lr][lk * 8];
      #pragma unroll
      for (int n = 0; n < 8; ++n){
        bf16x8 bk8 = *(const bf16x8*)&Ks[kk][16 * n + lr][lk * 8];
        accs[n] = __builtin_amdgcn_mfma_f32_16x16x32_bf16(aq, bk8, accs[n], 0, 0, 0);
      }
    }

    #pragma unroll
    for (int n = 0; n < 8; ++n)
      #pragma unroll
      for (int r = 0; r < 4; ++r) accs[n][r] *= 0.125f;
    float mnew[4], alpha[4], psum[4];
    #pragma unroll
    for (int r = 0; r < 4; ++r){
      float mx = accs[0][r];
      #pragma unroll
      for (int n = 1; n < 8; ++n) mx = fmaxf(mx, accs[n][r]);
      #pragma unroll
      for (int o = 1; o < 16; o <<= 1) mx = fmaxf(mx, __shfl_xor(mx, o));
      mnew[r] = fmaxf(m_[r], mx);
      alpha[r] = __expf(m_[r] - mnew[r]);
      m_[r] = mnew[r];
      psum[r] = 0.f;
    }
    #pragma unroll
    for (int n = 0; n < 8; ++n){
      #pragma unroll
      for (int r = 0; r < 4; ++r){
        float p = __expf(accs[n][r] - mnew[r]);
        psum[r] += p;
        Ps[w][n >> 1][lk * 4 + r][16 * (n & 1) + lr] = f2bf(p);
      }
    }
    #pragma unroll
    for (int r = 0; r < 4; ++r){
      float s = psum[r];
      #pragma unroll
      for (int o = 1; o < 16; o <<= 1) s += __shfl_xor(s, o);
      l_[r] = l_[r] * alpha[r] + s;
      #pragma unroll
      for (int n = 0; n < 4; ++n) acc_o[n][r] *= alpha[r];
    }

    #pragma unroll
    for (int kk = 0; kk < 4; ++kk){
      bf16x8 ap = *(const bf16x8*)&Ps[w][kk][lr][lk * 8];
      #pragma unroll
      for (int n = 0; n < 4; ++n){
        bf16x8 bv8 = *(const bf16x8*)&Vt[kk][16 * n + lr][lk * 8];
        acc_o[n] = __builtin_amdgcn_mfma_f32_16x16x32_bf16(ap, bv8, acc_o[n], 0, 0, 0);
      }
    }
  }

  #pragma unroll
  for (int n = 0; n < 4; ++n){
    #pragma unroll
    for (int r = 0; r < 4; ++r){
      size_t off = ((size_t)(b * kS + qt * 64 + 16 * w + lk * 4 + r)) * kD + h * 64 + 16 * n + lr;
      ao[off] = f2bf(acc_o[n][r] / l_[r]);
    }
  }
}

} // namespace

extern "C" void kernel_launch(void* const* d_in, const int* in_sizes, int n_in,
                              void* d_out, int out_size, void* d_ws, size_t ws_size,
                              hipStream_t stream){
  (void)in_sizes; (void)n_in; (void)out_size;
  const float* x    = (const float*)d_in[0];
  const float* memk = (const float*)d_in[1];
  const float* memv = (const float*)d_in[2];
  const float* n1   = (const float*)d_in[3];
  const float* n2   = (const float*)d_in[4];
  const float* wq   = (const float*)d_in[5];   const float* bq  = (const float*)d_in[6];
  const float* wk   = (const float*)d_in[7];   const float* bk  = (const float*)d_in[8];
  const float* wv   = (const float*)d_in[9];   const float* bv  = (const float*)d_in[10];
  const float* wz   = (const float*)d_in[11];  const float* bz  = (const float*)d_in[12];
  const float* wgz  = (const float*)d_in[13];  const float* bgz = (const float*)d_in[14];
  const float* wgh  = (const float*)d_in[15];  const float* bgh = (const float*)d_in[16];
  const float* wg1  = (const float*)d_in[17];  const float* bg1 = (const float*)d_in[18];
  const float* wg2  = (const float*)d_in[19];  const float* bg2 = (const float*)d_in[20];
  const float* wc1  = (const float*)d_in[21];  const float* bc1 = (const float*)d_in[22];
  const float* wc2  = (const float*)d_in[23];  const float* bc2 = (const float*)d_in[24];
  const float* wak  = (const float*)d_in[25];  const float* bak = (const float*)d_in[26];
  const float* wav  = (const float*)d_in[27];  const float* bav = (const float*)d_in[28];
  const float* wao  = (const float*)d_in[29];  const float* bao = (const float*)d_in[30];
  const float* w1   = (const float*)d_in[31];  const float* b1  = (const float*)d_in[32];
  const float* w2   = (const float*)d_in[33];  const float* b2  = (const float*)d_in[34];
  float* outp = (float*)d_out;
  char* ws = (char*)d_ws;
  const size_t MBy = 1024ull * 1024ull;
  if (ws_size < 252 * MBy) return; // need 252MB scratch

  // ---- workspace layout (time-multiplexed regions) ----
  unsigned short* wq_t  = (unsigned short*)(ws + 0 * MBy);   // wq/wk/wv/wz contiguous: fused N=4096 Bt
  unsigned short* wk_t  = (unsigned short*)(ws + 2 * MBy);
  unsigned short* wv_t  = (unsigned short*)(ws + 4 * MBy);
  unsigned short* wz_t  = (unsigned short*)(ws + 6 * MBy);
  unsigned short* wgz_t = (unsigned short*)(ws + 8 * MBy);
  unsigned short* wak_t = (unsigned short*)(ws + 10 * MBy);
  unsigned short* wav_t = (unsigned short*)(ws + 12 * MBy);
  unsigned short* wao_t = (unsigned short*)(ws + 14 * MBy);
  unsigned short* wg1_t = (unsigned short*)(ws + 16 * MBy);
  unsigned short* wg2_t = (unsigned short*)(ws + 16 * MBy + 524288);
  unsigned short* wc1_t = (unsigned short*)(ws + 16 * MBy + 2 * 524288);
  unsigned short* wc2_t = (unsigned short*)(ws + 16 * MBy + 3 * 524288);
  unsigned short* w1_t  = (unsigned short*)(ws + 18 * MBy);
  unsigned short* w2_t  = (unsigned short*)(ws + 26 * MBy);
  unsigned long long* hpub = (unsigned long long*)(ws + 34 * MBy); // 64KB
  unsigned short* xn    = (unsigned short*)(ws + 40 * MBy);
  unsigned short* memk_b= (unsigned short*)(ws + 40 * MBy);
  unsigned short* memv_b= (unsigned short*)(ws + 48 * MBy);
  unsigned short* ao    = (unsigned short*)(ws + 40 * MBy);   // after kh/vhT GEMMs consume memk_b/memv_b
  unsigned short* qb_   = (unsigned short*)(ws + 56 * MBy);
  unsigned short* xn2   = (unsigned short*)(ws + 56 * MBy);
  unsigned short* kb_   = (unsigned short*)(ws + 72 * MBy);
  unsigned short* khb   = (unsigned short*)(ws + 72 * MBy);
  unsigned short* vhT   = (unsigned short*)(ws + 80 * MBy);   // [b][h][d][key] 8MB
  unsigned short* vb_   = (unsigned short*)(ws + 88 * MBy);
  float*          zf    = (float*)(ws + 104 * MBy);
  unsigned short* zb_   = (unsigned short*)(ws + 136 * MBy);
  unsigned short* mid   = (unsigned short*)(ws + 136 * MBy);
  float*          gzf   = (float*)(ws + 152 * MBy);
  float*          gmf   = (float*)(ws + 184 * MBy);
  unsigned short* g1b   = (unsigned short*)(ws + 216 * MBy);
  float*          xres  = (float*)(ws + 220 * MBy);

  dim3 tb(32, 8);
  // ---- weight transposes (wgh consumed directly by k_scan) ----
  k_transpose_bf16<<<dim3(32, 32), tb, 0, stream>>>(wq,  wq_t,  1024, 1024);
  k_transpose_bf16<<<dim3(32, 32), tb, 0, stream>>>(wk,  wk_t,  1024, 1024);
  k_transpose_bf16<<<dim3(32, 32), tb, 0, stream>>>(wv,  wv_t,  1024, 1024);
  k_transpose_bf16<<<dim3(32, 32), tb, 0, stream>>>(wz,  wz_t,  1024, 1024);
  k_transpose_bf16<<<dim3(32, 32), tb, 0, stream>>>(wgz, wgz_t, 1024, 1024);
  k_transpose_bf16<<<dim3(32, 32), tb, 0, stream>>>(wak, wak_t, 1024, 1024);
  k_transpose_bf16<<<dim3(32, 32), tb, 0, stream>>>(wav, wav_t, 1024, 1024);
  k_transpose_bf16<<<dim3(32, 32), tb, 0, stream>>>(wao, wao_t, 1024, 1024);
  k_transpose_bf16<<<dim3(8, 32),  tb, 0, stream>>>(wg1, wg1_t, 1024, 256);
  k_transpose_bf16<<<dim3(32, 8),  tb, 0, stream>>>(wg2, wg2_t, 256, 1024);
  k_transpose_bf16<<<dim3(8, 32),  tb, 0, stream>>>(wc1, wc1_t, 1024, 256);
  k_transpose_bf16<<<dim3(32, 8),  tb, 0, stream>>>(wc2, wc2_t, 256, 1024);
  k_transpose_bf16<<<dim3(128, 32),tb, 0, stream>>>(w1,  w1_t,  1024, 4096);
  k_transpose_bf16<<<dim3(32, 128),tb, 0, stream>>>(w2,  w2_t,  4096, 1024);

  // ---- norm + fused q/k/v/z projection ----
  k_rmsnorm<<<kBS, 256, 0, stream>>>(x, n1, xn);
  gemm_kernel<8><<<dim3(32, 64), 256, 0, stream>>>(xn, 1024, wq_t, 1024, bq, zf, qb_, nullptr,
                                                   kBS, 4096, 1024, bk, bv, bz, kb_, vb_, zb_);

  // ---- gate_z_seq and gamma ----
  gemm_kernel<0><<<dim3(8, 64), 256, 0, stream>>>(zb_, 1024, wgz_t, 1024, bgz, gzf, nullptr, nullptr, kBS, 1024, 1024);
  gemm_kernel<2><<<dim3(2, 64), 256, 0, stream>>>(zb_, 1024, wg1_t, 1024, bg1, nullptr, g1b, nullptr, kBS, 256, 1024);
  gemm_kernel<3><<<dim3(8, 64), 256, 0, stream>>>(g1b, 256, wg2_t, 256, bg2, gmf, nullptr, nullptr, kBS, 1024, 256);
  gemm_kernel<2><<<dim3(2, 64), 256, 0, stream>>>(kb_, 1024, wc1_t, 1024, bc1, nullptr, g1b, nullptr, kBS, 256, 1024);
  gemm_kernel<4><<<dim3(8, 64), 256, 0, stream>>>(g1b, 256, wc2_t, 256, bc2, gmf, nullptr, nullptr, kBS, 1024, 256);

  // ---- sequential scan (h written in-place over z; hpub re-tagged each launch) ----
  hipMemsetAsync(hpub, 0xFF, 65536, stream);
  k_scan<<<128, 256, 0, stream>>>(wgh, gzf, zf, gmf, bgh, hpub);

  // ---- memory attention (MFMA flash; V written transposed by EPI 9) ----
  k_f32_to_bf16<<<1024, 256, 0, stream>>>(memk, memk_b, kBM * kD / 4);
  k_f32_to_bf16<<<1024, 256, 0, stream>>>(memv, memv_b, kBM * kD / 4);
  gemm_kernel<1><<<dim3(8, 32), 256, 0, stream>>>(memk_b, 1024, wak_t, 1024, bak, nullptr, khb, nullptr, kBM, 1024, 1024);
  gemm_kernel<9><<<dim3(8, 32), 256, 0, stream>>>(memv_b, 1024, wav_t, 1024, bav, nullptr, vhT, nullptr, kBM, 1024, 1024);
  k_attn_mfma<<<dim3(32, 16, 4), 256, 0, stream>>>(qb_, khb, vhT, ao);
  gemm_kernel<0><<<dim3(8, 64), 256, 0, stream>>>(ao, 1024, wao_t, 1024, bao, xres, nullptr, nullptr, kBS, 1024, 1024);

  // ---- combine + norm2 + FFN (F split in two 2048 chunks to bound scratch) ----
  k_combine<<<2048, 256, 0, stream>>>(xres, x, zf, vb_, kBS * kD / 4);
  k_rmsnorm<<<kBS, 256, 0, stream>>>(xres, n2, xn2);
  gemm_kernel<2><<<dim3(16, 64), 256, 0, stream>>>(xn2, 1024, w1_t, 1024, b1, nullptr, mid, nullptr, kBS, 2048, 1024);
  gemm_kernel<6><<<dim3(8, 64), 256, 0, stream>>>(mid, 2048, w2_t, 4096, b2, outp, nullptr, xres, kBS, 1024, 2048);
  gemm_kernel<2><<<dim3(16, 64), 256, 0, stream>>>(xn2, 1024, w1_t + (size_t)2048 * 1024, 1024, b1 + 2048, nullptr, mid, nullptr, kBS, 2048, 1024);
  gemm_kernel<7><<<dim3(8, 64), 256, 0, stream>>>(mid, 2048, w2_t + 2048, 4096, nullptr, outp, nullptr, nullptr, kBS, 1024, 2048);
}